// Round 23
// baseline (38.987 us; speedup 1.0000x reference)
//
#include <hip/hip_runtime.h>
#include <hip/hip_bf16.h>
#include <math.h>

#define P65 65
#define PLANE_U16 5248        // 5120 frag + 80 side + 48 pad (10496 B)
#define SIDE_OFF  5120
#define PSI_U16   8320        // 64*65 fp32 = 16640 B
#define IMG_U16   (PLANE_U16 + PSI_U16)   // 13568 u16 = 27136 B per image slot

// ---- device tables (built by init_tables each launch; deterministic) ----
// gAfrag: 18 blocks of 512 (analysis Gf 0..9, synthesis Gt 10..17); lane l holds
// Tbl[16*blkrow + (l&15)][32*kt + 8*(l>>4) + e]. Used as the MFMA *B* operand.
__device__ __align__(16) ushort gAfrag[18*512];
__device__ float  g_MpPad[65*68]; // NEGATED spectral multiplier, padded stride 68 ([k2][k1])
__device__ float  g64tab[65];     // G[64][j] = sin(2*pi*32*j/65); [64] pad

__device__ __constant__ float c_DOMAIN[8] = {0.75f,1.0f,0.75f,1.0f,0.75f,1.0f,0.75f,1.0f};

// RNE float -> bf16 bits via HW conversion path (R22-proven).
__device__ inline ushort f2bf(float f) {
  return __bfloat16_as_ushort(__float2bfloat16(f));
}
__device__ inline float bf2f(ushort h) { return __uint_as_float(((unsigned)h) << 16); }

// Raw barrier (R17-proven): LDS drained, global loads stay in flight; sched pinned.
__device__ inline void barrier_lds() {
  asm volatile("s_waitcnt lgkmcnt(0)" ::: "memory");
  __builtin_amdgcn_sched_barrier(0);
  __builtin_amdgcn_s_barrier();
  __builtin_amdgcn_sched_barrier(0);
}

// fp32 trig with exact integer angle reduction (prod mod 65).
__device__ inline float Gvalf(int r, int i) {
  int m = (r <= 32) ? r : (r - 32);
  int prod = (m * (i % 65)) % 65;
  float ang = 6.2831853071795864769f * (float)prod / 65.0f;
  return (r <= 32) ? cosf(ang) : sinf(ang);
}
__device__ inline float Gfoldf(int r, int i) {    // wrap-fold: += G[r][64] at i==0
  float v = Gvalf(r, i);
  if (i == 0) v += Gvalf(r, 64);
  return v;
}

__global__ void init_tables() {
  int tid = blockIdx.x*blockDim.x + threadIdx.x;
  int nth = gridDim.x*blockDim.x;
  for (int idx = tid; idx < 18*512; idx += nth) {
    int blk = idx >> 9, rem = idx & 511;
    int lane = rem >> 3, e = rem & 7;
    int i16 = lane & 15, kg = lane >> 4;
    float v = 0.f;
    if (blk < 10) {
      int mt = blk >> 1, kt = blk & 1;
      int r = 16*mt + i16;
      int i = 32*kt + 8*kg + e;
      if (r < 65 && i < 64) v = Gfoldf(r, i);
    } else {
      int b2 = blk - 10;
      int mt = b2 >> 1, kt = b2 & 1;
      int j  = 16*mt + i16;
      int k1 = 32*kt + 8*kg + e;
      if (j < 64 && k1 < 64) v = Gvalf(k1, j);
    }
    gAfrag[idx] = f2bf(v);
  }
  for (int idx = tid; idx < 65*68; idx += nth) {
    int k2 = idx/68, k1 = idx%68;
    float v = 0.f;
    if (k1 <= 64 && (k1 | k2)) {
      float n1 = (k1==0)?(1.0f/65.0f):(2.0f/65.0f);
      float n2 = (k2==0)?(1.0f/65.0f):(2.0f/65.0f);
      int m1 = (k1<=32)?k1:(k1-32), m2 = (k2<=32)?k2:(k2-32);
      float b1 = 6.2831853071795864769f*(float)m1/65.0f;
      float b2 = 6.2831853071795864769f*(float)m2/65.0f;
      v = (n1*n2)/(b1*b1 + b2*b2);     // NEGATED vs true Mp (sign folded: we store x, not -x)
    }
    g_MpPad[idx] = v;
  }
  for (int idx = tid; idx < 65; idx += nth)
    g64tab[idx] = (idx < 64) ? Gvalf(64, idx) : 0.f;
}

typedef __attribute__((ext_vector_type(8))) short bf16x8;
typedef __attribute__((ext_vector_type(4))) float f32x4;

// Table prefetch for the wave's first 2 tiles (issued before the preceding barrier).
// Shared by both images' stage calls in the phase.
template<int JT, int TBLOFF>
__device__ inline void prefetchA(bf16x8 (&pre)[2][2], int wvu, int lane, int NTL) {
  #pragma unroll
  for (int tb = 0; tb < 2; ++tb) {
    int tile = wvu + 8*tb;
    int tl = (tile < NTL) ? tile : 0;
    int jt = tl % JT;
    #pragma unroll
    for (int kt = 0; kt < 2; ++kt)
      pre[tb][kt] = *(const bf16x8*)(gAfrag + (TBLOFF + jt*2 + kt)*512 + lane*8);
  }
}

// One transform stage, operand-swapped (R19/R22-proven, verbatim): D = data(A) x table(B)^T.
template<int IT, int JT, int TBLOFF, bool SCALE, bool RK, bool PSI>
__device__ inline void stage(const bf16x8 (&pre)[2][2],
                             const ushort* __restrict__ Lin,
                             ushort* __restrict__ Lout,
                             float* __restrict__ psiout,
                             int wvu, int lane)
{
  const int lg = lane >> 4, li = lane & 15;
  constexpr int NTL = IT*JT;
  constexpr int TPW = (NTL + 7) >> 3;
  #pragma unroll
  for (int tb = 0; tb < TPW; ++tb) {
    const int tile = wvu + 8*tb;
    if (tile >= NTL) continue;            // wave-uniform skip
    const int it = tile / JT, jt = tile - it*JT;
    f32x4 acc = {0.f, 0.f, 0.f, 0.f};
    #pragma unroll
    for (int kt = 0; kt < 2; ++kt) {
      bf16x8 af = (tb < 2) ? pre[tb][kt]
                           : *(const bf16x8*)(gAfrag + (TBLOFF + jt*2 + kt)*512 + lane*8);
      bf16x8 df = *(const bf16x8*)(Lin + (it*2 + kt)*512 + lane*8);
      acc = __builtin_amdgcn_mfma_f32_16x16x32_bf16(df, af, acc, 0, 0, 0);  // data first!
    }
    const int f     = 16*jt + li;         // table/output-col index
    const int dbase = 16*it + 4*lg;       // data/output-row base
    const bool dEdge = (IT == 5) && (it == IT-1);   // only d==64 (lg==0, r==0) valid
    const bool fEdge = (JT == 5) && (jt == JT-1);   // only f==64 (li==0) valid

    float v[4];
    #pragma unroll
    for (int r = 0; r < 4; ++r) v[r] = acc[r];

    if (SCALE) {
      const float* mp = g_MpPad + (fEdge ? 64 : f)*68 + (dEdge ? 64 : dbase);
      if (dEdge) v[0] *= mp[0];
      else {
        f32x4 m4 = *(const f32x4*)mp;      // aligned: 68*f*4B % 16 == 0, dbase%4==0
        #pragma unroll
        for (int r = 0; r < 4; ++r) v[r] *= m4[r];
      }
    }
    if (RK) {                              // rank-1 k=64 term; RK stages have f<=63
      float gv = g64tab[f];
      uint2 sc = *(const uint2*)(Lin + SIDE_OFF + dbase);   // 4 consecutive sidecar u16
      v[0] = fmaf(bf2f((ushort)(sc.x      )), gv, v[0]);
      v[1] = fmaf(bf2f((ushort)(sc.x >> 16)), gv, v[1]);
      v[2] = fmaf(bf2f((ushort)(sc.y      )), gv, v[2]);
      v[3] = fmaf(bf2f((ushort)(sc.y >> 16)), gv, v[3]);
    }

    if (PSI) {                             // S4: psi[j2=f][j1=dbase+r], stride-65 fp32
      #pragma unroll
      for (int r = 0; r < 4; ++r) psiout[f*65 + dbase + r] = v[r];
    } else if (dEdge) {                    // d==64 row -> sidecar[f]
      if (lg == 0 && (!fEdge || li == 0))
        Lout[SIDE_OFF + f] = f2bf(v[0]);
    } else {
      if (!fEdge || li == 0) {
        int wb = (2*jt + (it>>1))*512 + ((2*it + (lg>>1))&3)*128 + li*8 + 4*(lg&1);
        uint2 pk;
        pk.x = ((unsigned)f2bf(v[1]) << 16) | (unsigned)f2bf(v[0]);
        pk.y = ((unsigned)f2bf(v[3]) << 16) | (unsigned)f2bf(v[2]);
        *(uint2*)(Lout + wb) = pk;         // one aligned b64 store
      }
    }
  }
}

__device__ inline float shflx(float v, int srclane) { return __shfl(v, srclane, 64); }

// Stencil (R22-proven): psi[j][c] = Ppsi[c*65 + j]; own x rows from regs.
__device__ inline void stencil_img(const float* __restrict__ Ppsi,
                                   const float* __restrict__ xr,
                                   float xbm, float xbp,
                                   float mu, float id2,
                                   float* __restrict__ op,
                                   int wvu, int lane, bool store)
{
  const int c = lane, cm = (c+63)&63, cp = (c+1)&63;
  const int cB = c*65, cmB = cm*65, cpB = cp*65;
  const int j0 = wvu*8, jm0 = (j0+63)&63;

  float xm_c = xbm,   xm_m = shflx(xm_c, cm), xm_p = shflx(xm_c, cp);
  float xc_c = xr[0], xc_m = shflx(xc_c, cm), xc_p = shflx(xc_c, cp);
  float pm_m = Ppsi[cmB+jm0], pm_c = Ppsi[cB+jm0], pm_p = Ppsi[cpB+jm0];
  float pc_m = Ppsi[cmB+j0 ], pc_c = Ppsi[cB+j0 ], pc_p = Ppsi[cpB+j0 ];

  #pragma unroll
  for (int m=0;m<8;++m) {
    int j = j0 + m, jp = (j+1)&63;
    float xn_c = (m < 7) ? xr[m+1] : xbp;
    float xn_m = shflx(xn_c, cm), xn_p = shflx(xn_c, cp);
    float pn_m = Ppsi[cmB+jp], pn_c = Ppsi[cB+jp], pn_p = Ppsi[cpB+jp];

    float J1 = (pn_c - pm_c)*(xc_p - xc_m) - (pc_p - pc_m)*(xn_c - xm_c);
    float J2 = xc_p*(pn_p - pm_p) - xc_m*(pn_m - pm_m)
             - xn_c*(pn_p - pn_m) + xm_c*(pm_p - pm_m);
    float J3 = xn_p*(pn_c - pc_p) - xm_m*(pc_m - pm_c)
             - xn_m*(pn_c - pc_m) + xm_p*(pc_p - pm_c);
    float lap = (xm_c + xn_c + xc_m + xc_p + xn_m - 4.0f*xc_c) * id2;

    if (store) op[j*64 + c] = -(J1 + J2 + J3)*(0.25f/3.0f) + mu*lap;

    xm_m=xc_m; xm_c=xc_c; xm_p=xc_p;  pm_m=pc_m; pm_c=pc_c; pm_p=pc_p;
    xc_m=xn_m; xc_c=xn_c; xc_p=xn_p;  pc_m=pn_m; pc_c=pn_c; pc_p=pn_p;
  }
}

__global__ void __launch_bounds__(512) pde_main(const float* __restrict__ y0,
                                                const int*   __restrict__ env,
                                                const float* __restrict__ params,
                                                float*       __restrict__ out,
                                                int B)
{
  // Two image slots, each [PB (5248) | PA-region (8320)]; psi fp32 overlays dead PA at S4.
  // Chain per image: L->PA, S1 PA->PB, S2 PB->PA, S3 PA->PB, S4 PB->psi.
  // Both images advance one stage per barrier pair (phase bodies doubled, barriers/image halved).
  __shared__ __align__(16) ushort Lsh[2*IMG_U16];
  ushort* PB0 = Lsh;
  ushort* PA0 = Lsh + PLANE_U16;
  float*  Ps0 = (float*)(Lsh + PLANE_U16);
  ushort* PB1 = Lsh + IMG_U16;
  ushort* PA1 = Lsh + IMG_U16 + PLANE_U16;
  float*  Ps1 = (float*)(Lsh + IMG_U16 + PLANE_U16);

  const int t    = threadIdx.x;
  const int lane = t & 63;
  const int wvu  = __builtin_amdgcn_readfirstlane(t >> 6);

  const int b0  = 2*blockIdx.x;
  const int b1r = b0 + 1;
  const bool has2 = (b1r < B);
  const int b1 = has2 ? b1r : b0;

  const int   e0 = env[b0], e1 = env[b1];
  const float mu0 = params[2*e0], mu1 = params[2*e1];
  const float fdx0 = c_DOMAIN[e0] * (float)(3.14159265358979323846/64.0);
  const float fdx1 = c_DOMAIN[e1] * (float)(3.14159265358979323846/64.0);
  const float id20 = 1.0f/(fdx0*fdx0);
  const float id21 = 1.0f/(fdx1*fdx1);

  const float* xb0 = y0 + (size_t)b0*4096;
  const float* xb1 = y0 + (size_t)b1*4096;

  // ---- Phase L: both images; x transposed into frag layout, one b128 write each.
  //      Boundary rows + S1 table prefetch issued here (in flight across barriers).
  const int j0 = wvu*8, jm0 = (j0+63)&63, jp8 = (j0+8)&63;
  float xbm0 = xb0[jm0*64 + lane], xbp0 = xb0[jp8*64 + lane];
  float xbm1 = xb1[jm0*64 + lane], xbp1 = xb1[jp8*64 + lane];

  float xr0[8], xr1[8];
  {
    bf16x8 h0, h1;
    #pragma unroll
    for (int k=0;k<8;++k) {
      float v0 = xb0[(8*wvu + k)*64 + lane];
      float v1 = xb1[(8*wvu + k)*64 + lane];
      xr0[k] = v0;  h0[k] = (short)f2bf(v0);
      xr1[k] = v1;  h1[k] = (short)f2bf(v1);
    }
    int wb = ((lane>>4)*2 + (wvu>>2))*512 + ((wvu&3)*16 + (lane&15))*8;
    *(bf16x8*)(PA0 + wb) = h0;
    *(bf16x8*)(PA1 + wb) = h1;
  }
  bf16x8 p1[2][2];  prefetchA<5,0>(p1, wvu, lane, 20);
  barrier_lds();

  // ---- S1 (both images): D[c2][k1] = sum_j x[j][c2]*Gf[k1][j]   (IT=4, JT=5)
  stage<4,5, 0,false,false,false>(p1, PA0, PB0, nullptr, wvu, lane);
  stage<4,5, 0,false,false,false>(p1, PA1, PB1, nullptr, wvu, lane);
  bf16x8 p2[2][2];  prefetchA<5,0>(p2, wvu, lane, 25);
  barrier_lds();

  // ---- S2 (both): D[k1][k2] = MpN .* sum_c2 O1[k1][c2]*Gf[k2][c2]  (IT=5, JT=5)
  stage<5,5, 0,true ,false,false>(p2, PB0, PA0, nullptr, wvu, lane);
  stage<5,5, 0,true ,false,false>(p2, PB1, PA1, nullptr, wvu, lane);
  bf16x8 p3[2][2];  prefetchA<4,10>(p3, wvu, lane, 20);
  barrier_lds();

  // ---- S3 (both): D[k2][j1] = sum_k1 O2[k2][k1]*Gt[j1][k1] + rank1(k1=64)  (IT=5, JT=4)
  stage<5,4,10,false,true ,false>(p3, PA0, PB0, nullptr, wvu, lane);
  stage<5,4,10,false,true ,false>(p3, PA1, PB1, nullptr, wvu, lane);
  bf16x8 p4[2][2];  prefetchA<4,10>(p4, wvu, lane, 16);
  barrier_lds();

  // ---- S4 (both): psi[j1][j2] = sum_k2 V[j1][k2]*Gt[j2][k2] + rank1(k2=64)  (IT=4, JT=4)
  stage<4,4,10,false,true ,true >(p4, PB0, nullptr, Ps0, wvu, lane);
  stage<4,4,10,false,true ,true >(p4, PB1, nullptr, Ps1, wvu, lane);
  barrier_lds();

  // ---- stencils (no barrier between; wave-private after final barrier) ----
  stencil_img(Ps0, xr0, xbm0, xbp0, mu0, id20, out + (size_t)b0*4096, wvu, lane, true);
  stencil_img(Ps1, xr1, xbm1, xbp1, mu1, id21, out + (size_t)b1*4096, wvu, lane, has2);
}

extern "C" void kernel_launch(void* const* d_in, const int* in_sizes, int n_in,
                              void* d_out, int out_size, void* d_ws, size_t ws_size,
                              hipStream_t stream) {
  const float* y0     = (const float*)d_in[1];
  const int*   env    = (const int*)  d_in[2];
  const float* params = (const float*)d_in[3];
  float*       out    = (float*)d_out;
  int B = in_sizes[1] / 4096;
  int nb = (B + 1) / 2;

  init_tables<<<64, 256, 0, stream>>>();
  pde_main<<<nb, 512, 0, stream>>>(y0, env, params, out, B);
}

// Round 24
// 35.546 us; speedup vs baseline: 1.0968x; 1.0968x over previous
//
#include <hip/hip_runtime.h>
#include <hip/hip_bf16.h>
#include <math.h>

#define P65 65
#define PLANE_U16 5248        // 5120 frag + 80 side + 48 pad (10496 B)
#define SIDE_OFF  5120
#define PSI_U16   8320        // 64*65 fp32 = 16640 B

// ---- device tables (built by init_tables each launch; deterministic) ----
// gAfrag: 18 blocks of 512 (analysis Gf 0..9, synthesis Gt 10..17); lane l holds
// Tbl[16*blkrow + (l&15)][32*kt + 8*(l>>4) + e]. Used as the MFMA *B* operand.
__device__ __align__(16) ushort gAfrag[18*512];
__device__ float  g_MpPad[65*68]; // NEGATED spectral multiplier, padded stride 68 ([k2][k1])
__device__ float  g64tab[65];     // G[64][j] = sin(2*pi*32*j/65); [64] pad

__device__ __constant__ float c_DOMAIN[8] = {0.75f,1.0f,0.75f,1.0f,0.75f,1.0f,0.75f,1.0f};

// RNE float -> bf16 bits via HW conversion path (R22-proven).
__device__ inline ushort f2bf(float f) {
  return __bfloat16_as_ushort(__float2bfloat16(f));
}
__device__ inline float bf2f(ushort h) { return __uint_as_float(((unsigned)h) << 16); }

// Raw barrier (R17-proven): LDS drained, global loads stay in flight; sched pinned.
__device__ inline void barrier_lds() {
  asm volatile("s_waitcnt lgkmcnt(0)" ::: "memory");
  __builtin_amdgcn_sched_barrier(0);
  __builtin_amdgcn_s_barrier();
  __builtin_amdgcn_sched_barrier(0);
}

// fp32 trig with exact integer angle reduction (prod mod 65).
__device__ inline float Gvalf(int r, int i) {
  int m = (r <= 32) ? r : (r - 32);
  int prod = (m * (i % 65)) % 65;
  float ang = 6.2831853071795864769f * (float)prod / 65.0f;
  return (r <= 32) ? cosf(ang) : sinf(ang);
}
__device__ inline float Gfoldf(int r, int i) {    // wrap-fold: += G[r][64] at i==0
  float v = Gvalf(r, i);
  if (i == 0) v += Gvalf(r, 64);
  return v;
}

__global__ void init_tables() {
  int tid = blockIdx.x*blockDim.x + threadIdx.x;
  int nth = gridDim.x*blockDim.x;
  for (int idx = tid; idx < 18*512; idx += nth) {
    int blk = idx >> 9, rem = idx & 511;
    int lane = rem >> 3, e = rem & 7;
    int i16 = lane & 15, kg = lane >> 4;
    float v = 0.f;
    if (blk < 10) {
      int mt = blk >> 1, kt = blk & 1;
      int r = 16*mt + i16;
      int i = 32*kt + 8*kg + e;
      if (r < 65 && i < 64) v = Gfoldf(r, i);
    } else {
      int b2 = blk - 10;
      int mt = b2 >> 1, kt = b2 & 1;
      int j  = 16*mt + i16;
      int k1 = 32*kt + 8*kg + e;
      if (j < 64 && k1 < 64) v = Gvalf(k1, j);
    }
    gAfrag[idx] = f2bf(v);
  }
  for (int idx = tid; idx < 65*68; idx += nth) {
    int k2 = idx/68, k1 = idx%68;
    float v = 0.f;
    if (k1 <= 64 && (k1 | k2)) {
      float n1 = (k1==0)?(1.0f/65.0f):(2.0f/65.0f);
      float n2 = (k2==0)?(1.0f/65.0f):(2.0f/65.0f);
      int m1 = (k1<=32)?k1:(k1-32), m2 = (k2<=32)?k2:(k2-32);
      float b1 = 6.2831853071795864769f*(float)m1/65.0f;
      float b2 = 6.2831853071795864769f*(float)m2/65.0f;
      v = (n1*n2)/(b1*b1 + b2*b2);     // NEGATED vs true Mp (sign folded: we store x, not -x)
    }
    g_MpPad[idx] = v;
  }
  for (int idx = tid; idx < 65; idx += nth)
    g64tab[idx] = (idx < 64) ? Gvalf(64, idx) : 0.f;
}

typedef __attribute__((ext_vector_type(8))) short bf16x8;
typedef __attribute__((ext_vector_type(4))) float f32x4;

// Table prefetch for the wave's first 3 tiles (issued before the preceding barrier;
// survives it — raw barriers don't drain vmcnt). Depth 3 covers S1/S3 fully (TPW=3),
// S2 3-of-4, S4 fully (TPW=2).
template<int JT, int TBLOFF>
__device__ inline void prefetchA(bf16x8 (&pre)[3][2], int wvu, int lane, int NTL) {
  #pragma unroll
  for (int tb = 0; tb < 3; ++tb) {
    int tile = wvu + 8*tb;
    int tl = (tile < NTL) ? tile : 0;
    int jt = tl % JT;
    #pragma unroll
    for (int kt = 0; kt < 2; ++kt)
      pre[tb][kt] = *(const bf16x8*)(gAfrag + (TBLOFF + jt*2 + kt)*512 + lane*8);
  }
}

// One transform stage, operand-swapped (R19/R22-proven): D = data(A) x table(B)^T.
// D rows = data index d (acc regs: d = 16*it + 4*lg + r), D cols = table index f = 16*jt + li.
// Output stored as frag(R=f, C=d): e = d&7 -> thread's 4 values are CONTIGUOUS -> one b64 store.
// Edge cases: d==64 rows (IT==5, it==4) -> u16 sidecar[f]; f==64 col (JT==5, jt==4) -> li==0 only.
template<int IT, int JT, int TBLOFF, bool SCALE, bool RK, bool PSI>
__device__ inline void stage(const bf16x8 (&pre)[3][2],
                             const ushort* __restrict__ Lin,
                             ushort* __restrict__ Lout,
                             float* __restrict__ psiout,
                             int wvu, int lane)
{
  const int lg = lane >> 4, li = lane & 15;
  constexpr int NTL = IT*JT;
  constexpr int TPW = (NTL + 7) >> 3;
  #pragma unroll
  for (int tb = 0; tb < TPW; ++tb) {
    const int tile = wvu + 8*tb;
    if (tile >= NTL) continue;            // wave-uniform skip
    const int it = tile / JT, jt = tile - it*JT;
    f32x4 acc = {0.f, 0.f, 0.f, 0.f};
    #pragma unroll
    for (int kt = 0; kt < 2; ++kt) {
      bf16x8 af = (tb < 3) ? pre[tb][kt]
                           : *(const bf16x8*)(gAfrag + (TBLOFF + jt*2 + kt)*512 + lane*8);
      bf16x8 df = *(const bf16x8*)(Lin + (it*2 + kt)*512 + lane*8);
      acc = __builtin_amdgcn_mfma_f32_16x16x32_bf16(df, af, acc, 0, 0, 0);  // data first!
    }
    const int f     = 16*jt + li;         // table/output-col index
    const int dbase = 16*it + 4*lg;       // data/output-row base
    const bool dEdge = (IT == 5) && (it == IT-1);   // only d==64 (lg==0, r==0) valid
    const bool fEdge = (JT == 5) && (jt == JT-1);   // only f==64 (li==0) valid

    float v[4];
    #pragma unroll
    for (int r = 0; r < 4; ++r) v[r] = acc[r];

    if (SCALE) {
      const float* mp = g_MpPad + (fEdge ? 64 : f)*68 + (dEdge ? 64 : dbase);
      if (dEdge) v[0] *= mp[0];
      else {
        f32x4 m4 = *(const f32x4*)mp;      // aligned: 68*f*4B % 16 == 0, dbase%4==0
        #pragma unroll
        for (int r = 0; r < 4; ++r) v[r] *= m4[r];
      }
    }
    if (RK) {                              // rank-1 k=64 term; RK stages have f<=63
      float gv = g64tab[f];
      uint2 sc = *(const uint2*)(Lin + SIDE_OFF + dbase);   // 4 consecutive sidecar u16
      v[0] = fmaf(bf2f((ushort)(sc.x      )), gv, v[0]);
      v[1] = fmaf(bf2f((ushort)(sc.x >> 16)), gv, v[1]);
      v[2] = fmaf(bf2f((ushort)(sc.y      )), gv, v[2]);
      v[3] = fmaf(bf2f((ushort)(sc.y >> 16)), gv, v[3]);
    }

    if (PSI) {                             // S4: psi[j2=f][j1=dbase+r], stride-65 fp32
      #pragma unroll
      for (int r = 0; r < 4; ++r) psiout[f*65 + dbase + r] = v[r];
    } else if (dEdge) {                    // d==64 row -> sidecar[f]
      if (lg == 0 && (!fEdge || li == 0))
        Lout[SIDE_OFF + f] = f2bf(v[0]);
    } else {
      if (!fEdge || li == 0) {
        int wb = (2*jt + (it>>1))*512 + ((2*it + (lg>>1))&3)*128 + li*8 + 4*(lg&1);
        uint2 pk;
        pk.x = ((unsigned)f2bf(v[1]) << 16) | (unsigned)f2bf(v[0]);
        pk.y = ((unsigned)f2bf(v[3]) << 16) | (unsigned)f2bf(v[2]);
        *(uint2*)(Lout + wb) = pk;         // one aligned b64 store
      }
    }
  }
}

__device__ inline float shflx(float v, int srclane) { return __shfl(v, srclane, 64); }

__global__ void __launch_bounds__(512) pde_main(const float* __restrict__ y0,
                                                const int*   __restrict__ env,
                                                const float* __restrict__ params,
                                                float*       __restrict__ out)
{
  // [PB (5248) | PA-region (8320)]. Chain: L->PA, S1 PA->PB, S2 PB->PA, S3 PA->PB,
  // S4 PB->psi (fp32 psi, layout [j2][j1] stride 65, overlays the dead PA region).
  __shared__ __align__(16) ushort Lsh[PLANE_U16 + PSI_U16];
  ushort* PB   = Lsh;
  ushort* PA   = Lsh + PLANE_U16;
  float*  Ppsi = (float*)(Lsh + PLANE_U16);

  const int b    = blockIdx.x;
  const int t    = threadIdx.x;
  const int lane = t & 63;
  const int wvu  = __builtin_amdgcn_readfirstlane(t >> 6);

  const int   e       = env[b];
  const float mu      = params[2*e];
  const float fdx     = c_DOMAIN[e] * (float)(3.14159265358979323846/64.0);
  const float inv_dx2 = 1.0f/(fdx*fdx);

  const float* xb = y0 + (size_t)b*4096;

  // ---- Phase L: x stored transposed into frag1(R=c, C=j) (sign folded into MpPad);
  //      one ds_write_b128 per thread. Boundary rows + S1 table prefetch issued here.
  const int j0 = wvu*8, jm0 = (j0+63)&63, jp8 = (j0+8)&63;
  float xbm = xb[jm0*64 + lane];
  float xbp = xb[jp8*64 + lane];

  float xr[8];
  bf16x8 hv;
  #pragma unroll
  for (int k=0;k<8;++k) {
    float v = xb[(8*wvu + k)*64 + lane];
    xr[k] = v;
    hv[k] = (short)f2bf(v);
  }
  {
    int wb = ((lane>>4)*2 + (wvu>>2))*512 + ((wvu&3)*16 + (lane&15))*8;
    *(bf16x8*)(PA + wb) = hv;
  }
  bf16x8 p1[3][2];  prefetchA<5,0>(p1, wvu, lane, 20);
  barrier_lds();

  // ---- S1: D[c2][k1] = sum_j x[j][c2]*Gf[k1][j]   (IT=4 over c2, JT=5 over k1)
  stage<4,5, 0,false,false,false>(p1, PA, PB, nullptr, wvu, lane);
  bf16x8 p2[3][2];  prefetchA<5,0>(p2, wvu, lane, 25);
  barrier_lds();

  // ---- S2: D[k1][k2] = MpN .* sum_c2 O1[k1][c2]*Gf[k2][c2]  (IT=5, JT=5)
  stage<5,5, 0,true ,false,false>(p2, PB, PA, nullptr, wvu, lane);
  bf16x8 p3[3][2];  prefetchA<4,10>(p3, wvu, lane, 20);
  barrier_lds();

  // ---- S3: D[k2][j1] = sum_k1 O2[k2][k1]*Gt[j1][k1] + rank1(k1=64)  (IT=5, JT=4)
  stage<5,4,10,false,true ,false>(p3, PA, PB, nullptr, wvu, lane);
  bf16x8 p4[3][2];  prefetchA<4,10>(p4, wvu, lane, 16);
  barrier_lds();

  // ---- S4: psi[j1][j2] = sum_k2 V[j1][k2]*Gt[j2][k2] + rank1(k2=64)  (IT=4, JT=4)
  stage<4,4,10,false,true ,true >(p4, PB, nullptr, Ppsi, wvu, lane);
  barrier_lds();

  // ---- stencil: psi[j][c] = Ppsi[c*65 + j]; own x rows from regs, boundary rows prefetched
  {
    const int c = lane, cm = (c+63)&63, cp = (c+1)&63;
    const int cB = c*65, cmB = cm*65, cpB = cp*65;
    float* op = out + (size_t)b*4096;

    float xm_c = xbm,   xm_m = shflx(xm_c, cm), xm_p = shflx(xm_c, cp);
    float xc_c = xr[0], xc_m = shflx(xc_c, cm), xc_p = shflx(xc_c, cp);
    float pm_m = Ppsi[cmB+jm0], pm_c = Ppsi[cB+jm0], pm_p = Ppsi[cpB+jm0];
    float pc_m = Ppsi[cmB+j0 ], pc_c = Ppsi[cB+j0 ], pc_p = Ppsi[cpB+j0 ];

    #pragma unroll
    for (int m=0;m<8;++m) {
      int j = j0 + m, jp = (j+1)&63;
      float xn_c = (m < 7) ? xr[m+1] : xbp;
      float xn_m = shflx(xn_c, cm), xn_p = shflx(xn_c, cp);
      float pn_m = Ppsi[cmB+jp], pn_c = Ppsi[cB+jp], pn_p = Ppsi[cpB+jp];

      float J1 = (pn_c - pm_c)*(xc_p - xc_m) - (pc_p - pc_m)*(xn_c - xm_c);
      float J2 = xc_p*(pn_p - pm_p) - xc_m*(pn_m - pm_m)
               - xn_c*(pn_p - pn_m) + xm_c*(pm_p - pm_m);
      float J3 = xn_p*(pn_c - pc_p) - xm_m*(pc_m - pm_c)
               - xn_m*(pn_c - pc_m) + xm_p*(pc_p - pm_c);
      float lap = (xm_c + xn_c + xc_m + xc_p + xn_m - 4.0f*xc_c) * inv_dx2;

      op[j*64 + c] = -(J1 + J2 + J3)*(0.25f/3.0f) + mu*lap;

      xm_m=xc_m; xm_c=xc_c; xm_p=xc_p;  pm_m=pc_m; pm_c=pc_c; pm_p=pc_p;
      xc_m=xn_m; xc_c=xn_c; xc_p=xn_p;  pc_m=pn_m; pc_c=pn_c; pc_p=pn_p;
    }
  }
}

extern "C" void kernel_launch(void* const* d_in, const int* in_sizes, int n_in,
                              void* d_out, int out_size, void* d_ws, size_t ws_size,
                              hipStream_t stream) {
  const float* y0     = (const float*)d_in[1];
  const int*   env    = (const int*)  d_in[2];
  const float* params = (const float*)d_in[3];
  float*       out    = (float*)d_out;
  int B = in_sizes[1] / 4096;

  init_tables<<<64, 256, 0, stream>>>();
  pde_main<<<B, 512, 0, stream>>>(y0, env, params, out);
}

// Round 25
// 34.502 us; speedup vs baseline: 1.1300x; 1.0303x over previous
//
#include <hip/hip_runtime.h>
#include <hip/hip_bf16.h>
#include <math.h>

#define P65 65
#define PLANE_U16 5248        // 5120 frag + 80 side + 48 pad (10496 B)
#define SIDE_OFF  5120
#define PSI_U16   8320        // 64*65 fp32 = 16640 B

// ---- device tables (built by init_tables each launch; deterministic) ----
// gAfrag: 18 blocks of 512 (analysis Gf 0..9, synthesis Gt 10..17); lane l holds
// Tbl[16*blkrow + (l&15)][32*kt + 8*(l>>4) + e]. Used as the MFMA *B* operand.
__device__ __align__(16) ushort gAfrag[18*512];
__device__ float  g_MpPad[65*68]; // NEGATED spectral multiplier, padded stride 68 ([k2][k1])
__device__ float  g64tab[65];     // G[64][j] = sin(2*pi*32*j/65); [64] pad

__device__ __constant__ float c_DOMAIN[8] = {0.75f,1.0f,0.75f,1.0f,0.75f,1.0f,0.75f,1.0f};

// RNE float -> bf16 bits via HW conversion path (R22-proven).
__device__ inline ushort f2bf(float f) {
  return __bfloat16_as_ushort(__float2bfloat16(f));
}
__device__ inline float bf2f(ushort h) { return __uint_as_float(((unsigned)h) << 16); }

// Raw barrier (R17-proven): LDS drained, global loads stay in flight; sched pinned.
__device__ inline void barrier_lds() {
  asm volatile("s_waitcnt lgkmcnt(0)" ::: "memory");
  __builtin_amdgcn_sched_barrier(0);
  __builtin_amdgcn_s_barrier();
  __builtin_amdgcn_sched_barrier(0);
}

// fp32 trig with exact integer angle reduction (prod mod 65).
__device__ inline float Gvalf(int r, int i) {
  int m = (r <= 32) ? r : (r - 32);
  int prod = (m * (i % 65)) % 65;
  float ang = 6.2831853071795864769f * (float)prod / 65.0f;
  return (r <= 32) ? cosf(ang) : sinf(ang);
}
__device__ inline float Gfoldf(int r, int i) {    // wrap-fold: += G[r][64] at i==0
  float v = Gvalf(r, i);
  if (i == 0) v += Gvalf(r, 64);
  return v;
}

__global__ void init_tables() {
  int tid = blockIdx.x*blockDim.x + threadIdx.x;
  int nth = gridDim.x*blockDim.x;
  for (int idx = tid; idx < 18*512; idx += nth) {
    int blk = idx >> 9, rem = idx & 511;
    int lane = rem >> 3, e = rem & 7;
    int i16 = lane & 15, kg = lane >> 4;
    float v = 0.f;
    if (blk < 10) {
      int mt = blk >> 1, kt = blk & 1;
      int r = 16*mt + i16;
      int i = 32*kt + 8*kg + e;
      if (r < 65 && i < 64) v = Gfoldf(r, i);
    } else {
      int b2 = blk - 10;
      int mt = b2 >> 1, kt = b2 & 1;
      int j  = 16*mt + i16;
      int k1 = 32*kt + 8*kg + e;
      if (j < 64 && k1 < 64) v = Gvalf(k1, j);
    }
    gAfrag[idx] = f2bf(v);
  }
  for (int idx = tid; idx < 65*68; idx += nth) {
    int k2 = idx/68, k1 = idx%68;
    float v = 0.f;
    if (k1 <= 64 && (k1 | k2)) {
      float n1 = (k1==0)?(1.0f/65.0f):(2.0f/65.0f);
      float n2 = (k2==0)?(1.0f/65.0f):(2.0f/65.0f);
      int m1 = (k1<=32)?k1:(k1-32), m2 = (k2<=32)?k2:(k2-32);
      float b1 = 6.2831853071795864769f*(float)m1/65.0f;
      float b2 = 6.2831853071795864769f*(float)m2/65.0f;
      v = (n1*n2)/(b1*b1 + b2*b2);     // NEGATED vs true Mp (sign folded: we store x, not -x)
    }
    g_MpPad[idx] = v;
  }
  for (int idx = tid; idx < 65; idx += nth)
    g64tab[idx] = (idx < 64) ? Gvalf(64, idx) : 0.f;
}

typedef __attribute__((ext_vector_type(8))) short bf16x8;
typedef __attribute__((ext_vector_type(4))) float f32x4;

// Table prefetch for the wave's first 2 tiles (issued before the preceding barrier).
template<int JT, int TBLOFF>
__device__ inline void prefetchA(bf16x8 (&pre)[2][2], int wvu, int lane, int NTL) {
  #pragma unroll
  for (int tb = 0; tb < 2; ++tb) {
    int tile = wvu + 8*tb;
    int tl = (tile < NTL) ? tile : 0;
    int jt = tl % JT;
    #pragma unroll
    for (int kt = 0; kt < 2; ++kt)
      pre[tb][kt] = *(const bf16x8*)(gAfrag + (TBLOFF + jt*2 + kt)*512 + lane*8);
  }
}

// One transform stage, operand-swapped: D = data(A) x table(B)^T.
// D rows = data index d (acc regs: d = 16*it + 4*lg + r), D cols = table index f = 16*jt + li.
// Output stored as frag(R=f, C=d): e = d&7 -> thread's 4 values are CONTIGUOUS -> one b64 store.
// Edge cases: d==64 rows (IT==5, it==4) -> u16 sidecar[f]; f==64 col (JT==5, jt==4) -> li==0 only.
template<int IT, int JT, int TBLOFF, bool SCALE, bool RK, bool PSI>
__device__ inline void stage(const bf16x8 (&pre)[2][2],
                             const ushort* __restrict__ Lin,
                             ushort* __restrict__ Lout,
                             float* __restrict__ psiout,
                             int wvu, int lane)
{
  const int lg = lane >> 4, li = lane & 15;
  constexpr int NTL = IT*JT;
  constexpr int TPW = (NTL + 7) >> 3;
  #pragma unroll
  for (int tb = 0; tb < TPW; ++tb) {
    const int tile = wvu + 8*tb;
    if (tile >= NTL) continue;            // wave-uniform skip
    const int it = tile / JT, jt = tile - it*JT;
    f32x4 acc = {0.f, 0.f, 0.f, 0.f};
    #pragma unroll
    for (int kt = 0; kt < 2; ++kt) {
      bf16x8 af = (tb < 2) ? pre[tb][kt]
                           : *(const bf16x8*)(gAfrag + (TBLOFF + jt*2 + kt)*512 + lane*8);
      bf16x8 df = *(const bf16x8*)(Lin + (it*2 + kt)*512 + lane*8);
      acc = __builtin_amdgcn_mfma_f32_16x16x32_bf16(df, af, acc, 0, 0, 0);  // data first!
    }
    const int f     = 16*jt + li;         // table/output-col index
    const int dbase = 16*it + 4*lg;       // data/output-row base
    const bool dEdge = (IT == 5) && (it == IT-1);   // only d==64 (lg==0, r==0) valid
    const bool fEdge = (JT == 5) && (jt == JT-1);   // only f==64 (li==0) valid

    float v[4];
    #pragma unroll
    for (int r = 0; r < 4; ++r) v[r] = acc[r];

    if (SCALE) {
      const float* mp = g_MpPad + (fEdge ? 64 : f)*68 + (dEdge ? 64 : dbase);
      if (dEdge) v[0] *= mp[0];
      else {
        f32x4 m4 = *(const f32x4*)mp;      // aligned: 68*f*4B % 16 == 0, dbase%4==0
        #pragma unroll
        for (int r = 0; r < 4; ++r) v[r] *= m4[r];
      }
    }
    if (RK) {                              // rank-1 k=64 term; RK stages have f<=63
      float gv = g64tab[f];
      uint2 sc = *(const uint2*)(Lin + SIDE_OFF + dbase);   // 4 consecutive sidecar u16
      v[0] = fmaf(bf2f((ushort)(sc.x      )), gv, v[0]);
      v[1] = fmaf(bf2f((ushort)(sc.x >> 16)), gv, v[1]);
      v[2] = fmaf(bf2f((ushort)(sc.y      )), gv, v[2]);
      v[3] = fmaf(bf2f((ushort)(sc.y >> 16)), gv, v[3]);
    }

    if (PSI) {                             // S4: psi[j2=f][j1=dbase+r], stride-65 fp32
      #pragma unroll
      for (int r = 0; r < 4; ++r) psiout[f*65 + dbase + r] = v[r];
    } else if (dEdge) {                    // d==64 row -> sidecar[f]
      if (lg == 0 && (!fEdge || li == 0))
        Lout[SIDE_OFF + f] = f2bf(v[0]);
    } else {
      if (!fEdge || li == 0) {
        int wb = (2*jt + (it>>1))*512 + ((2*it + (lg>>1))&3)*128 + li*8 + 4*(lg&1);
        uint2 pk;
        pk.x = ((unsigned)f2bf(v[1]) << 16) | (unsigned)f2bf(v[0]);
        pk.y = ((unsigned)f2bf(v[3]) << 16) | (unsigned)f2bf(v[2]);
        *(uint2*)(Lout + wb) = pk;         // one aligned b64 store
      }
    }
  }
}

__device__ inline float shflx(float v, int srclane) { return __shfl(v, srclane, 64); }

__global__ void __launch_bounds__(512) pde_main(const float* __restrict__ y0,
                                                const int*   __restrict__ env,
                                                const float* __restrict__ params,
                                                float*       __restrict__ out)
{
  // [PB (5248) | PA-region (8320)]. Chain: L->PA, S1 PA->PB, S2 PB->PA, S3 PA->PB,
  // S4 PB->psi (fp32 psi, layout [j2][j1] stride 65, overlays the dead PA region).
  __shared__ __align__(16) ushort Lsh[PLANE_U16 + PSI_U16];
  ushort* PB   = Lsh;
  ushort* PA   = Lsh + PLANE_U16;
  float*  Ppsi = (float*)(Lsh + PLANE_U16);

  const int b    = blockIdx.x;
  const int t    = threadIdx.x;
  const int lane = t & 63;
  const int wvu  = __builtin_amdgcn_readfirstlane(t >> 6);

  const int   e       = env[b];
  const float mu      = params[2*e];
  const float fdx     = c_DOMAIN[e] * (float)(3.14159265358979323846/64.0);
  const float inv_dx2 = 1.0f/(fdx*fdx);

  const float* xb = y0 + (size_t)b*4096;

  // ---- Phase L: x stored transposed into frag1(R=c, C=j) (sign folded into MpPad);
  //      one ds_write_b128 per thread. Boundary rows + S1 table prefetch issued here.
  const int j0 = wvu*8, jm0 = (j0+63)&63, jp8 = (j0+8)&63;
  float xbm = xb[jm0*64 + lane];
  float xbp = xb[jp8*64 + lane];

  float xr[8];
  bf16x8 hv;
  #pragma unroll
  for (int k=0;k<8;++k) {
    float v = xb[(8*wvu + k)*64 + lane];
    xr[k] = v;
    hv[k] = (short)f2bf(v);
  }
  {
    int wb = ((lane>>4)*2 + (wvu>>2))*512 + ((wvu&3)*16 + (lane&15))*8;
    *(bf16x8*)(PA + wb) = hv;
  }
  bf16x8 p1[2][2];  prefetchA<5,0>(p1, wvu, lane, 20);
  barrier_lds();

  // ---- S1: D[c2][k1] = sum_j x[j][c2]*Gf[k1][j]   (IT=4 over c2, JT=5 over k1)
  stage<4,5, 0,false,false,false>(p1, PA, PB, nullptr, wvu, lane);
  bf16x8 p2[2][2];  prefetchA<5,0>(p2, wvu, lane, 25);
  barrier_lds();

  // ---- S2: D[k1][k2] = MpN .* sum_c2 O1[k1][c2]*Gf[k2][c2]  (IT=5, JT=5)
  stage<5,5, 0,true ,false,false>(p2, PB, PA, nullptr, wvu, lane);
  bf16x8 p3[2][2];  prefetchA<4,10>(p3, wvu, lane, 20);
  barrier_lds();

  // ---- S3: D[k2][j1] = sum_k1 O2[k2][k1]*Gt[j1][k1] + rank1(k1=64)  (IT=5, JT=4)
  stage<5,4,10,false,true ,false>(p3, PA, PB, nullptr, wvu, lane);
  bf16x8 p4[2][2];  prefetchA<4,10>(p4, wvu, lane, 16);
  barrier_lds();

  // ---- S4: psi[j1][j2] = sum_k2 V[j1][k2]*Gt[j2][k2] + rank1(k2=64)  (IT=4, JT=4)
  stage<4,4,10,false,true ,true >(p4, PB, nullptr, Ppsi, wvu, lane);
  barrier_lds();

  // ---- stencil: psi[j][c] = Ppsi[c*65 + j]; own x rows from regs, boundary rows prefetched
  {
    const int c = lane, cm = (c+63)&63, cp = (c+1)&63;
    const int cB = c*65, cmB = cm*65, cpB = cp*65;
    float* op = out + (size_t)b*4096;

    float xm_c = xbm,   xm_m = shflx(xm_c, cm), xm_p = shflx(xm_c, cp);
    float xc_c = xr[0], xc_m = shflx(xc_c, cm), xc_p = shflx(xc_c, cp);
    float pm_m = Ppsi[cmB+jm0], pm_c = Ppsi[cB+jm0], pm_p = Ppsi[cpB+jm0];
    float pc_m = Ppsi[cmB+j0 ], pc_c = Ppsi[cB+j0 ], pc_p = Ppsi[cpB+j0 ];

    #pragma unroll
    for (int m=0;m<8;++m) {
      int j = j0 + m, jp = (j+1)&63;
      float xn_c = (m < 7) ? xr[m+1] : xbp;
      float xn_m = shflx(xn_c, cm), xn_p = shflx(xn_c, cp);
      float pn_m = Ppsi[cmB+jp], pn_c = Ppsi[cB+jp], pn_p = Ppsi[cpB+jp];

      float J1 = (pn_c - pm_c)*(xc_p - xc_m) - (pc_p - pc_m)*(xn_c - xm_c);
      float J2 = xc_p*(pn_p - pm_p) - xc_m*(pn_m - pm_m)
               - xn_c*(pn_p - pn_m) + xm_c*(pm_p - pm_m);
      float J3 = xn_p*(pn_c - pc_p) - xm_m*(pc_m - pm_c)
               - xn_m*(pn_c - pc_m) + xm_p*(pc_p - pm_c);
      float lap = (xm_c + xn_c + xc_m + xc_p + xn_m - 4.0f*xc_c) * inv_dx2;

      op[j*64 + c] = -(J1 + J2 + J3)*(0.25f/3.0f) + mu*lap;

      xm_m=xc_m; xm_c=xc_c; xm_p=xc_p;  pm_m=pc_m; pm_c=pc_c; pm_p=pc_p;
      xc_m=xn_m; xc_c=xn_c; xc_p=xn_p;  pc_m=pn_m; pc_c=pn_c; pc_p=pn_p;
    }
  }
}

extern "C" void kernel_launch(void* const* d_in, const int* in_sizes, int n_in,
                              void* d_out, int out_size, void* d_ws, size_t ws_size,
                              hipStream_t stream) {
  const float* y0     = (const float*)d_in[1];
  const int*   env    = (const int*)  d_in[2];
  const float* params = (const float*)d_in[3];
  float*       out    = (float*)d_out;
  int B = in_sizes[1] / 4096;

  init_tables<<<64, 256, 0, stream>>>();
  pde_main<<<B, 512, 0, stream>>>(y0, env, params, out);
}